// Round 22
// baseline (108.590 us; speedup 1.0000x reference)
//
#include <hip/hip_runtime.h>
#include <stdint.h>

typedef unsigned short u16;
typedef __attribute__((ext_vector_type(8))) short short8;
typedef __attribute__((ext_vector_type(4))) float f32x4;
typedef __attribute__((ext_vector_type(2))) uint32_t u32x2;

#define B_      16
#define L_      1024
#define H_      1024
#define G_      128
#define M_TOT   16368            // B*(L-1)
#define K_TOT   3072
#define OUT_SEG 2095104          // M_TOT*G_
#define KL_IDX  (4*OUT_SEG)
#define KL_BLOCKS 2046           // M_TOT / 8 exactly

// ws layout
#define WS_WT_OFF    0           // bf16 W'T [512][3072] = 3,145,728 B
#define WS_BIAS_OFF  3145728     // float[512]
#define WS_PART_OFF  3147776     // float[2046] block partials

__device__ inline u16 f2bf(float f) {
    union { float f; uint32_t u; } x; x.f = f;
    uint32_t u = x.u;
    return (u16)((u + 0x7fffu + ((u >> 16) & 1u)) >> 16);
}

__device__ inline void gload16(const void* g, void* l) {
    __builtin_amdgcn_global_load_lds(
        (const __attribute__((address_space(1))) void*)g,
        (__attribute__((address_space(3))) void*)l, 16, 0, 0);
}

// ---------------- prep: build W'T (bf16, [512][3072]) + bias[512] ------------
__global__ __launch_bounds__(256) void prep_kernel(
    const float* __restrict__ Wzm, const float* __restrict__ bzm,
    const float* __restrict__ Wzv, const float* __restrict__ bzv,
    const float* __restrict__ Wqm, const float* __restrict__ bqm,
    const float* __restrict__ Wqv, const float* __restrict__ bqv,
    u16* __restrict__ wt, float* __restrict__ bias)
{
    const int ng = blockIdx.x >> 2;
    const int kq = blockIdx.x & 3;
    const int n0 = ng * 8;
    const float* W; const float* bsrc; int g0; int kmax;
    if (n0 < 128)      { W = Wzm; bsrc = bzm; g0 = n0;       kmax = 2048; }
    else if (n0 < 256) { W = Wzv; bsrc = bzv; g0 = n0 - 128; kmax = 2048; }
    else if (n0 < 384) { W = Wqm; bsrc = bqm; g0 = n0 - 256; kmax = 3072; }
    else               { W = Wqv; bsrc = bqv; g0 = n0 - 384; kmax = 3072; }
    const int tid = threadIdx.x;
    if (kq == 0 && tid < 8) bias[n0 + tid] = bsrc[g0 + tid];

    __shared__ float lt[8][260];
    const int go = tid & 7;
    const int kk = tid >> 3;
    const int nn = tid >> 5;
    const int kc = (tid & 31) * 8;

    for (int i = 0; i < 3; ++i) {
        int kbase = kq * 768 + i * 256;
        __syncthreads();
        #pragma unroll
        for (int kk2 = 0; kk2 < 8; ++kk2) {
            int k = kbase + kk2 * 32 + kk;
            float v = (k < kmax) ? W[(size_t)k * G_ + g0 + go] : 0.0f;
            lt[go][kk2 * 32 + kk] = v;
        }
        __syncthreads();
        union { short8 s; u16 u[8]; } o;
        #pragma unroll
        for (int j = 0; j < 8; ++j) o.u[j] = f2bf(lt[nn][kc + j]);
        *(short8*)&wt[(size_t)(n0 + nn) * K_TOT + kbase + kc] = o.s;
    }
}

// ---------------- GEMM: out[m, 0:512] = ce @ W' + bias ----------------------
// R21 geometry (BM=128, BN=128, BK=64, 512 thr, 8 waves of 64x32, grid 512
// -> 2 blocks/CU, 16 waves/CU) with ONE barrier per phase:
//   { LOADA(t+2); WAITV(6); LGKM0; BAR; compute(t); stageB(t+2); CVTW(t+1) }
// A ring-2 (LDS slots), B ring-3; LDS = 2*16 + 3*16 = 80 KB (2 blocks/CU).
// Hazards: B DMA drained by each wave's own WAITV BEFORE the BAR that
// precedes compute; CVTW writes drained by NEXT phase's LGKM0 pre-BAR;
// stageB(t+2) -> slot (t-1)%3 issued after compute(t), all readers
// (compute(t-1)) joined at this phase's BAR. FIFO: queue at WAITV =
// {B(t)2, A(t+1)4, B(t+1)2, A(t+2)4} -> WAITV(6).
__global__ __launch_bounds__(512, 2) void gemm_kernel(
    const float* __restrict__ events, const float* __restrict__ contexts,
    const u16* __restrict__ wt, const float* __restrict__ bias,
    float* __restrict__ out)
{
    __shared__ u16 Ab[2][128 * 64];   // bf16 A tiles, swizzled (16 KB each)
    __shared__ u16 Bs[3][128 * 64];   // bf16 B tiles, swizzled (16 KB each)

    const int tid = threadIdx.x;
    const int bid = blockIdx.x;
    // 4 nb-blocks of an A panel share bid&7 -> same XCD.
    const int xx  = bid & 7;
    const int jj  = bid >> 3;            // 0..63
    const int nb  = jj & 3;
    const int mp  = (jj >> 2) * 8 + xx;  // 0..127
    const int m0  = mp * 128;

    const int lane = tid & 63;
    const int w    = tid >> 6;           // 0..7
    const int wm   = (w >> 2) * 64;      // 0 or 64
    const int wn   = (w & 3) * 32;       // 0,32,64,96
    const int lr   = lane & 15;
    const int kg   = lane >> 4;          // octet 0..3

    // ---- A staging: row r = tid>>2 (0..127), quarter q = tid&3 ----
    const int r = tid >> 2;
    const int q = tid & 3;
    int m = m0 + r; if (m > M_TOT - 1) m = M_TOT - 1;
    int bb = m / 1023;
    int tt = m - bb * 1023;
    const float* paE = events   + ((size_t)(bb * L_ + tt)) * H_;
    const float* paC = contexts + ((size_t)(bb * (L_ - 1) + tt)) * H_;
    int aw[4];
    #pragma unroll
    for (int j = 0; j < 4; ++j)
        aw[j] = r * 64 + (((2 * j + (q >> 1)) ^ (r & 7)) << 3) + (q & 1) * 4;

    // ---- B staging: 2 chunks/thread, source-preswizzled ----
    const u16* bS[2];
    #pragma unroll
    for (int it = 0; it < 2; ++it) {
        int c  = it * 512 + tid;         // 0..1023
        int v  = c >> 3;
        int cs = (c & 7) ^ (v & 7);
        bS[it] = wt + (size_t)(nb * 128 + v) * K_TOT + cs * 8;
    }

    // ---- fragment read offsets (u16, swizzled; chunk cw = ks*4+kg) ----
    int aoff[4][2], boff[2][2];
    #pragma unroll
    for (int i = 0; i < 4; ++i) {
        int row = wm + i * 16 + lr;
        #pragma unroll
        for (int ks = 0; ks < 2; ++ks)
            aoff[i][ks] = row * 64 + (((ks * 4 + kg) ^ (row & 7)) << 3);
    }
    #pragma unroll
    for (int j = 0; j < 2; ++j) {
        int nn = wn + j * 16 + lr;
        #pragma unroll
        for (int ks = 0; ks < 2; ++ks)
            boff[j][ks] = nn * 64 + (((ks * 4 + kg) ^ (nn & 7)) << 3);
    }

    f32x4 acc[4][2];
    #pragma unroll
    for (int i = 0; i < 4; ++i)
        #pragma unroll
        for (int j = 0; j < 2; ++j)
            acc[i][j] = (f32x4){0.f, 0.f, 0.f, 0.f};

    auto stageB = [&](int buf, int kt) {
        int k0 = kt * 64;
        gload16(bS[0] + k0, &Bs[buf][tid * 8]);
        gload16(bS[1] + k0, &Bs[buf][(512 + tid) * 8]);
    };
    auto compute = [&](int abuf, int bbuf) {
        #pragma unroll
        for (int ks = 0; ks < 2; ++ks) {
            short8 a[4], bf[2];
            #pragma unroll
            for (int i = 0; i < 4; ++i)
                a[i] = *(const short8*)&Ab[abuf][aoff[i][ks]];
            #pragma unroll
            for (int j = 0; j < 2; ++j)
                bf[j] = *(const short8*)&Bs[bbuf][boff[j][ks]];
            __builtin_amdgcn_s_setprio(1);
            #pragma unroll
            for (int i = 0; i < 4; ++i)
                #pragma unroll
                for (int j = 0; j < 2; ++j)
                    acc[i][j] = __builtin_amdgcn_mfma_f32_16x16x32_bf16(
                        a[i], bf[j], acc[i][j], 0, 0, 0);
            __builtin_amdgcn_s_setprio(0);
        }
    };

    // Named A-staging register sets (2-phase-deep; no arrays -> no scratch)
    f32x4 P0, P1, P2, P3;
    f32x4 Q0, Q1, Q2, Q3;

#define LOADA(p, KT)                                                           \
    {                                                                          \
        int k0_ = (KT) * 64;                                                   \
        int rg_ = (KT) >> 4;                                                   \
        int kq_ = (k0_ & 1023) + q * 4;                                        \
        const float* s_ = (rg_ == 0) ? paE : (rg_ == 1 ? (paE + H_) : paC);    \
        s_ += kq_;                                                             \
        p##0 = *(const f32x4*)(s_ +  0);                                       \
        p##1 = *(const f32x4*)(s_ + 16);                                       \
        p##2 = *(const f32x4*)(s_ + 32);                                       \
        p##3 = *(const f32x4*)(s_ + 48);                                       \
    }
#define CVT1(p, J, BUF)                                                        \
    {                                                                          \
        uint32_t lo_, hi_;                                                     \
        asm("v_cvt_pk_bf16_f32 %0, %1, %2" : "=v"(lo_) : "v"(p##J[0]), "v"(p##J[1])); \
        asm("v_cvt_pk_bf16_f32 %0, %1, %2" : "=v"(hi_) : "v"(p##J[2]), "v"(p##J[3])); \
        *(u32x2*)&Ab[BUF][aw[J]] = (u32x2){lo_, hi_};                          \
    }
#define CVTW(p, BUF)  CVT1(p, 0, BUF) CVT1(p, 1, BUF) CVT1(p, 2, BUF) CVT1(p, 3, BUF)

#define WAITV(N)                                                               \
    asm volatile("s_waitcnt vmcnt(" #N ")" ::: "memory");                      \
    __builtin_amdgcn_sched_barrier(0);
#define LGKM0                                                                  \
    asm volatile("s_waitcnt lgkmcnt(0)" ::: "memory");                         \
    __builtin_amdgcn_sched_barrier(0);
#define BARS                                                                   \
    __builtin_amdgcn_s_barrier();                                              \
    __builtin_amdgcn_sched_barrier(0);

// PHASE t: A compute slot AC=t%2, B compute slot BC=t%3,
//          B stage slot BS2=(t+2)%3; PL loaded (A(t+2)), PC cvt'd (A(t+1)).
#define PHASE(KT, AC, BC, BS2, PL, PC)                                         \
    LOADA(PL, (KT) + 2);                                                       \
    WAITV(6); LGKM0; BARS;                                                     \
    compute(AC, BC);                                                           \
    stageB(BS2, (KT) + 2);                                                     \
    CVTW(PC, (AC) ^ 1);

    // prologue: A(0)->regs->Ab[0]; B(0)->Bs[0]; Q=A(1), B(1)->Bs[1] in flight
    LOADA(P, 0);
    stageB(0, 0);
    WAITV(2);            // drain P = A(0) regs, leave B(0)
    CVTW(P, 0);
    LOADA(Q, 1);
    stageB(1, 1);        // queue: B0[2], A1[4], B1[2] = 8

    for (int t = 0; t < 42; t += 6) {
        PHASE(t,     0, 0, 2, P, Q);
        PHASE(t + 1, 1, 1, 0, Q, P);
        PHASE(t + 2, 0, 2, 1, P, Q);
        PHASE(t + 3, 1, 0, 2, Q, P);
        PHASE(t + 4, 0, 1, 0, P, Q);
        PHASE(t + 5, 1, 2, 1, Q, P);
    }
    PHASE(42, 0, 0, 2, P, Q);
    PHASE(43, 1, 1, 0, Q, P);
    PHASE(44, 0, 2, 1, P, Q);
    PHASE(45, 1, 0, 2, Q, P);
    // phase 46: queue = {B46[2], A47[4], B47[2]} -> drain B46+A47
    WAITV(2); LGKM0; BARS;
    compute(0, 1);
    CVTW(Q, 1);
    // phase 47
    WAITV(0); LGKM0; BARS;
    compute(1, 2);

#undef PHASE
#undef LOADA
#undef CVT1
#undef CVTW
#undef WAITV
#undef LGKM0
#undef BARS

    // epilogue: row = m0 + wm + i*16 + kg*4 + rr ; gcol = nb*128 + wn + j*16 + lr
    const float* bptr = bias + nb * 128;
    float* obase = out + (size_t)nb * OUT_SEG;
    #pragma unroll
    for (int i = 0; i < 4; ++i) {
        int mloc = wm + i * 16 + kg * 4;
        #pragma unroll
        for (int j = 0; j < 2; ++j) {
            int g = wn + j * 16 + lr;
            float bv = bptr[g];
            #pragma unroll
            for (int rr = 0; rr < 4; ++rr) {
                int mo = m0 + mloc + rr;
                if (mo < M_TOT) obase[(size_t)mo * G_ + g] = acc[i][j][rr] + bv;
            }
        }
    }
}

// ---------------- KL reduction: stage 1 (f32x4 loads, 8 rows/block) ----------
__global__ __launch_bounds__(256) void kl_kernel(const float* __restrict__ out,
                                                 float* __restrict__ partial)
{
    int row  = blockIdx.x * 8 + (threadIdx.x >> 5);   // 2046*8 = M_TOT
    int col  = (threadIdx.x & 31) * 4;
    const float* zm  = out;
    const float* zlv = out + OUT_SEG;
    const float* qm  = out + (size_t)2 * OUT_SEG;
    const float* qlv = out + (size_t)3 * OUT_SEG;
    size_t base = (size_t)row * G_ + col;
    f32x4 a = *(const f32x4*)&zm[base];
    f32x4 b = *(const f32x4*)&zlv[base];
    f32x4 c = *(const f32x4*)&qm[base];
    f32x4 d = *(const f32x4*)&qlv[base];
    float s = 0.f;
    #pragma unroll
    for (int e = 0; e < 4; ++e) {
        float diff = a[e] - c[e];
        s += d[e] - b[e] + (__expf(b[e]) + diff * diff) * __expf(-d[e]) - 1.0f;
    }
    #pragma unroll
    for (int off = 32; off > 0; off >>= 1)
        s += __shfl_down(s, off);
    __shared__ float pw[4];
    int wid  = threadIdx.x >> 6;
    int lane = threadIdx.x & 63;
    if (lane == 0) pw[wid] = s;
    __syncthreads();
    if (threadIdx.x == 0)
        partial[blockIdx.x] = pw[0] + pw[1] + pw[2] + pw[3];
}

// ---------------- KL reduction: stage 2 --------------------------------------
__global__ __launch_bounds__(256) void kl_final(const float* __restrict__ partial,
                                                float* __restrict__ out)
{
    float s = 0.f;
    for (int i = threadIdx.x; i < KL_BLOCKS; i += 256) s += partial[i];
    #pragma unroll
    for (int off = 32; off > 0; off >>= 1)
        s += __shfl_down(s, off);
    __shared__ float pw[4];
    int wid = threadIdx.x >> 6;
    int lane = threadIdx.x & 63;
    if (lane == 0) pw[wid] = s;
    __syncthreads();
    if (threadIdx.x == 0)
        out[KL_IDX] = 0.5f * (pw[0] + pw[1] + pw[2] + pw[3]) / (float)M_TOT;
}

// ---------------- launcher ----------------------------------------------------
extern "C" void kernel_launch(void* const* d_in, const int* in_sizes, int n_in,
                              void* d_out, int out_size, void* d_ws, size_t ws_size,
                              hipStream_t stream)
{
    const float* events   = (const float*)d_in[0];
    const float* contexts = (const float*)d_in[1];
    const float* Wzm = (const float*)d_in[2];
    const float* bzm = (const float*)d_in[3];
    const float* Wzv = (const float*)d_in[4];
    const float* bzv = (const float*)d_in[5];
    const float* Wqm = (const float*)d_in[6];
    const float* bqm = (const float*)d_in[7];
    const float* Wqv = (const float*)d_in[8];
    const float* bqv = (const float*)d_in[9];
    float* out = (float*)d_out;

    u16*   wt      = (u16*)((char*)d_ws + WS_WT_OFF);
    float* bias    = (float*)((char*)d_ws + WS_BIAS_OFF);
    float* partial = (float*)((char*)d_ws + WS_PART_OFF);

    prep_kernel<<<256, 256, 0, stream>>>(Wzm, bzm, Wzv, bzv, Wqm, bqm, Wqv, bqv,
                                         wt, bias);
    gemm_kernel<<<512, 512, 0, stream>>>(events, contexts, wt, bias, out);
    kl_kernel<<<KL_BLOCKS, 256, 0, stream>>>(out, partial);
    kl_final<<<1, 256, 0, stream>>>(partial, out);
}

// Round 23
// 94.837 us; speedup vs baseline: 1.1450x; 1.1450x over previous
//
#include <hip/hip_runtime.h>
#include <stdint.h>

typedef unsigned short u16;
typedef __attribute__((ext_vector_type(8))) short short8;
typedef __attribute__((ext_vector_type(4))) float f32x4;
typedef __attribute__((ext_vector_type(2))) uint32_t u32x2;

#define B_      16
#define L_      1024
#define H_      1024
#define G_      128
#define M_TOT   16368            // B*(L-1)
#define K_TOT   3072
#define OUT_SEG 2095104          // M_TOT*G_
#define KL_IDX  (4*OUT_SEG)
#define KL_BLOCKS 2046           // M_TOT / 8 exactly

// ws layout
#define WS_WT_OFF    0           // bf16 W'T [512][3072] = 3,145,728 B
#define WS_BIAS_OFF  3145728     // float[512]
#define WS_PART_OFF  3147776     // float[2046] block partials

__device__ inline u16 f2bf(float f) {
    union { float f; uint32_t u; } x; x.f = f;
    uint32_t u = x.u;
    return (u16)((u + 0x7fffu + ((u >> 16) & 1u)) >> 16);
}

__device__ inline void gload16(const void* g, void* l) {
    __builtin_amdgcn_global_load_lds(
        (const __attribute__((address_space(1))) void*)g,
        (__attribute__((address_space(3))) void*)l, 16, 0, 0);
}

// ---------------- prep: build W'T (bf16, [512][3072]) + bias[512] ------------
__global__ __launch_bounds__(256) void prep_kernel(
    const float* __restrict__ Wzm, const float* __restrict__ bzm,
    const float* __restrict__ Wzv, const float* __restrict__ bzv,
    const float* __restrict__ Wqm, const float* __restrict__ bqm,
    const float* __restrict__ Wqv, const float* __restrict__ bqv,
    u16* __restrict__ wt, float* __restrict__ bias)
{
    const int ng = blockIdx.x >> 2;
    const int kq = blockIdx.x & 3;
    const int n0 = ng * 8;
    const float* W; const float* bsrc; int g0; int kmax;
    if (n0 < 128)      { W = Wzm; bsrc = bzm; g0 = n0;       kmax = 2048; }
    else if (n0 < 256) { W = Wzv; bsrc = bzv; g0 = n0 - 128; kmax = 2048; }
    else if (n0 < 384) { W = Wqm; bsrc = bqm; g0 = n0 - 256; kmax = 3072; }
    else               { W = Wqv; bsrc = bqv; g0 = n0 - 384; kmax = 3072; }
    const int tid = threadIdx.x;
    if (kq == 0 && tid < 8) bias[n0 + tid] = bsrc[g0 + tid];

    __shared__ float lt[8][260];
    const int go = tid & 7;
    const int kk = tid >> 3;
    const int nn = tid >> 5;
    const int kc = (tid & 31) * 8;

    for (int i = 0; i < 3; ++i) {
        int kbase = kq * 768 + i * 256;
        __syncthreads();
        #pragma unroll
        for (int kk2 = 0; kk2 < 8; ++kk2) {
            int k = kbase + kk2 * 32 + kk;
            float v = (k < kmax) ? W[(size_t)k * G_ + g0 + go] : 0.0f;
            lt[go][kk2 * 32 + kk] = v;
        }
        __syncthreads();
        union { short8 s; u16 u[8]; } o;
        #pragma unroll
        for (int j = 0; j < 8; ++j) o.u[j] = f2bf(lt[nn][kc + j]);
        *(short8*)&wt[(size_t)(n0 + nn) * K_TOT + kbase + kc] = o.s;
    }
}

// ---------------- GEMM: out[m, 0:512] = ce @ W' + bias ----------------------
// R21 champion (94.1 us total), byte-identical restore.
// BM=128, BN=128, BK=64, 512 threads (8 waves, 2x4 grid of 64x32 sub-tiles),
// grid 512 -> 2 blocks/CU = 16 waves/CU.
//   A: global f32x4 (4 threads/row) -> named P/Q reg sets (2-deep) ->
//      cvt_pk bf16 -> swizzled ds_write_b64.
//   B: global_load_lds source-preswizzled.
// LDS = 2*(16KB A + 16KB B) = 64KB. Counted vmcnt: 6 VMEM/thread/phase
// (4 A + 2 B); WAITV(6) drains exactly {B(t), Aregs(t+1)}.
// Swizzle: rows = 128B = 8 chunks of 16B, chunk ^= (row&7).
__global__ __launch_bounds__(512, 2) void gemm_kernel(
    const float* __restrict__ events, const float* __restrict__ contexts,
    const u16* __restrict__ wt, const float* __restrict__ bias,
    float* __restrict__ out)
{
    __shared__ u16 Ab[2][128 * 64];   // bf16 A tiles, swizzled (16 KB each)
    __shared__ u16 Bs[2][128 * 64];   // bf16 B tiles, swizzled (16 KB each)

    const int tid = threadIdx.x;
    const int bid = blockIdx.x;
    // 4 nb-blocks of an A panel share bid&7 -> same XCD.
    const int xx  = bid & 7;
    const int jj  = bid >> 3;            // 0..63
    const int nb  = jj & 3;
    const int mp  = (jj >> 2) * 8 + xx;  // 0..127
    const int m0  = mp * 128;

    const int lane = tid & 63;
    const int w    = tid >> 6;           // 0..7
    const int wm   = (w >> 2) * 64;      // 0 or 64
    const int wn   = (w & 3) * 32;       // 0,32,64,96
    const int lr   = lane & 15;
    const int kg   = lane >> 4;          // octet 0..3

    // ---- A staging: row r = tid>>2 (0..127), quarter q = tid&3 ----
    const int r = tid >> 2;
    const int q = tid & 3;
    int m = m0 + r; if (m > M_TOT - 1) m = M_TOT - 1;
    int bb = m / 1023;
    int tt = m - bb * 1023;
    const float* paE = events   + ((size_t)(bb * L_ + tt)) * H_;
    const float* paC = contexts + ((size_t)(bb * (L_ - 1) + tt)) * H_;
    // swizzled ds_write_b64 offsets: load j -> chunk 2j+(q>>1), +4 if q odd
    int aw[4];
    #pragma unroll
    for (int j = 0; j < 4; ++j)
        aw[j] = r * 64 + (((2 * j + (q >> 1)) ^ (r & 7)) << 3) + (q & 1) * 4;

    // ---- B staging: 2 chunks/thread, source-preswizzled ----
    const u16* bS[2];
    #pragma unroll
    for (int it = 0; it < 2; ++it) {
        int c  = it * 512 + tid;         // 0..1023
        int v  = c >> 3;
        int cs = (c & 7) ^ (v & 7);
        bS[it] = wt + (size_t)(nb * 128 + v) * K_TOT + cs * 8;
    }

    // ---- fragment read offsets (u16, swizzled; chunk cw = ks*4+kg) ----
    int aoff[4][2], boff[2][2];
    #pragma unroll
    for (int i = 0; i < 4; ++i) {
        int row = wm + i * 16 + lr;
        #pragma unroll
        for (int ks = 0; ks < 2; ++ks)
            aoff[i][ks] = row * 64 + (((ks * 4 + kg) ^ (row & 7)) << 3);
    }
    #pragma unroll
    for (int j = 0; j < 2; ++j) {
        int nn = wn + j * 16 + lr;
        #pragma unroll
        for (int ks = 0; ks < 2; ++ks)
            boff[j][ks] = nn * 64 + (((ks * 4 + kg) ^ (nn & 7)) << 3);
    }

    f32x4 acc[4][2];
    #pragma unroll
    for (int i = 0; i < 4; ++i)
        #pragma unroll
        for (int j = 0; j < 2; ++j)
            acc[i][j] = (f32x4){0.f, 0.f, 0.f, 0.f};

    auto stageB = [&](int buf, int kt) {
        int k0 = kt * 64;
        gload16(bS[0] + k0, &Bs[buf][tid * 8]);
        gload16(bS[1] + k0, &Bs[buf][(512 + tid) * 8]);
    };
    auto compute = [&](int buf) {
        #pragma unroll
        for (int ks = 0; ks < 2; ++ks) {
            short8 a[4], bf[2];
            #pragma unroll
            for (int i = 0; i < 4; ++i)
                a[i] = *(const short8*)&Ab[buf][aoff[i][ks]];
            #pragma unroll
            for (int j = 0; j < 2; ++j)
                bf[j] = *(const short8*)&Bs[buf][boff[j][ks]];
            __builtin_amdgcn_s_setprio(1);
            #pragma unroll
            for (int i = 0; i < 4; ++i)
                #pragma unroll
                for (int j = 0; j < 2; ++j)
                    acc[i][j] = __builtin_amdgcn_mfma_f32_16x16x32_bf16(
                        a[i], bf[j], acc[i][j], 0, 0, 0);
            __builtin_amdgcn_s_setprio(0);
        }
    };

    // Named A-staging register sets (2-phase-deep; no arrays -> no scratch)
    f32x4 P0, P1, P2, P3;
    f32x4 Q0, Q1, Q2, Q3;

#define LOADA(p, KT)                                                           \
    {                                                                          \
        int k0_ = (KT) * 64;                                                   \
        int rg_ = (KT) >> 4;                                                   \
        int kq_ = (k0_ & 1023) + q * 4;                                        \
        const float* s_ = (rg_ == 0) ? paE : (rg_ == 1 ? (paE + H_) : paC);    \
        s_ += kq_;                                                             \
        p##0 = *(const f32x4*)(s_ +  0);                                       \
        p##1 = *(const f32x4*)(s_ + 16);                                       \
        p##2 = *(const f32x4*)(s_ + 32);                                       \
        p##3 = *(const f32x4*)(s_ + 48);                                       \
    }
#define CVT1(p, J, BUF)                                                        \
    {                                                                          \
        uint32_t lo_, hi_;                                                     \
        asm("v_cvt_pk_bf16_f32 %0, %1, %2" : "=v"(lo_) : "v"(p##J[0]), "v"(p##J[1])); \
        asm("v_cvt_pk_bf16_f32 %0, %1, %2" : "=v"(hi_) : "v"(p##J[2]), "v"(p##J[3])); \
        *(u32x2*)&Ab[BUF][aw[J]] = (u32x2){lo_, hi_};                          \
    }
#define CVTW(p, BUF)  CVT1(p, 0, BUF) CVT1(p, 1, BUF) CVT1(p, 2, BUF) CVT1(p, 3, BUF)

#define WAITV(N)                                                               \
    asm volatile("s_waitcnt vmcnt(" #N ")" ::: "memory");                      \
    __builtin_amdgcn_sched_barrier(0);
#define LGKM0                                                                  \
    asm volatile("s_waitcnt lgkmcnt(0)" ::: "memory");                         \
    __builtin_amdgcn_sched_barrier(0);
#define BAR __builtin_amdgcn_s_barrier()

    // prologue: A(0)->regs->Ab[0]; B(0) in flight; A(1)->Q (in flight)
    LOADA(P, 0);
    stageB(0, 0);
    WAITV(2);            // drain P = A(0) regs, leave B(0)
    CVTW(P, 0);
    LOADA(Q, 1);         // outstanding: B(0) 2 + Q 4 = 6
    LGKM0;               // prologue ds_writes done before first barrier

    for (int t = 0; t < 46; t += 2) {
        // phase t (buf0): consume Q=A(t+1) after WAITV
        LOADA(P, t + 2);
        stageB(1, t + 1);
        WAITV(6); BAR;                 // drains B(t) + Q regs
        compute(0);
        CVTW(Q, 1);
        LGKM0; BAR;
        // phase t+1 (buf1)
        LOADA(Q, t + 3);
        stageB(0, t + 2);
        WAITV(6); BAR;                 // drains B(t+1) + P regs
        compute(1);
        CVTW(P, 0);
        LGKM0; BAR;
    }
    // phase 46 (buf0): Q holds A(47); no more A loads
    stageB(1, 47);
    WAITV(2); BAR;                     // drains B(46) + Q regs, leaves B(47)
    compute(0);
    CVTW(Q, 1);
    LGKM0; BAR;
    // phase 47 (buf1)
    WAITV(0); BAR;
    compute(1);

#undef LOADA
#undef CVT1
#undef CVTW
#undef WAITV
#undef LGKM0
#undef BAR

    // epilogue: row = m0 + wm + i*16 + kg*4 + rr ; gcol = nb*128 + wn + j*16 + lr
    const float* bptr = bias + nb * 128;
    float* obase = out + (size_t)nb * OUT_SEG;
    #pragma unroll
    for (int i = 0; i < 4; ++i) {
        int mloc = wm + i * 16 + kg * 4;
        #pragma unroll
        for (int j = 0; j < 2; ++j) {
            int g = wn + j * 16 + lr;
            float bv = bptr[g];
            #pragma unroll
            for (int rr = 0; rr < 4; ++rr) {
                int mo = m0 + mloc + rr;
                if (mo < M_TOT) obase[(size_t)mo * G_ + g] = acc[i][j][rr] + bv;
            }
        }
    }
}

// ---------------- KL reduction: stage 1 (f32x4 loads, 8 rows/block) ----------
__global__ __launch_bounds__(256) void kl_kernel(const float* __restrict__ out,
                                                 float* __restrict__ partial)
{
    int row  = blockIdx.x * 8 + (threadIdx.x >> 5);   // 2046*8 = M_TOT
    int col  = (threadIdx.x & 31) * 4;
    const float* zm  = out;
    const float* zlv = out + OUT_SEG;
    const float* qm  = out + (size_t)2 * OUT_SEG;
    const float* qlv = out + (size_t)3 * OUT_SEG;
    size_t base = (size_t)row * G_ + col;
    f32x4 a = *(const f32x4*)&zm[base];
    f32x4 b = *(const f32x4*)&zlv[base];
    f32x4 c = *(const f32x4*)&qm[base];
    f32x4 d = *(const f32x4*)&qlv[base];
    float s = 0.f;
    #pragma unroll
    for (int e = 0; e < 4; ++e) {
        float diff = a[e] - c[e];
        s += d[e] - b[e] + (__expf(b[e]) + diff * diff) * __expf(-d[e]) - 1.0f;
    }
    #pragma unroll
    for (int off = 32; off > 0; off >>= 1)
        s += __shfl_down(s, off);
    __shared__ float pw[4];
    int wid  = threadIdx.x >> 6;
    int lane = threadIdx.x & 63;
    if (lane == 0) pw[wid] = s;
    __syncthreads();
    if (threadIdx.x == 0)
        partial[blockIdx.x] = pw[0] + pw[1] + pw[2] + pw[3];
}

// ---------------- KL reduction: stage 2 --------------------------------------
__global__ __launch_bounds__(256) void kl_final(const float* __restrict__ partial,
                                                float* __restrict__ out)
{
    float s = 0.f;
    for (int i = threadIdx.x; i < KL_BLOCKS; i += 256) s += partial[i];
    #pragma unroll
    for (int off = 32; off > 0; off >>= 1)
        s += __shfl_down(s, off);
    __shared__ float pw[4];
    int wid = threadIdx.x >> 6;
    int lane = threadIdx.x & 63;
    if (lane == 0) pw[wid] = s;
    __syncthreads();
    if (threadIdx.x == 0)
        out[KL_IDX] = 0.5f * (pw[0] + pw[1] + pw[2] + pw[3]) / (float)M_TOT;
}

// ---------------- launcher ----------------------------------------------------
extern "C" void kernel_launch(void* const* d_in, const int* in_sizes, int n_in,
                              void* d_out, int out_size, void* d_ws, size_t ws_size,
                              hipStream_t stream)
{
    const float* events   = (const float*)d_in[0];
    const float* contexts = (const float*)d_in[1];
    const float* Wzm = (const float*)d_in[2];
    const float* bzm = (const float*)d_in[3];
    const float* Wzv = (const float*)d_in[4];
    const float* bzv = (const float*)d_in[5];
    const float* Wqm = (const float*)d_in[6];
    const float* bqm = (const float*)d_in[7];
    const float* Wqv = (const float*)d_in[8];
    const float* bqv = (const float*)d_in[9];
    float* out = (float*)d_out;

    u16*   wt      = (u16*)((char*)d_ws + WS_WT_OFF);
    float* bias    = (float*)((char*)d_ws + WS_BIAS_OFF);
    float* partial = (float*)((char*)d_ws + WS_PART_OFF);

    prep_kernel<<<256, 256, 0, stream>>>(Wzm, bzm, Wzv, bzv, Wqm, bqm, Wqv, bqv,
                                         wt, bias);
    gemm_kernel<<<512, 512, 0, stream>>>(events, contexts, wt, bias, out);
    kl_kernel<<<KL_BLOCKS, 256, 0, stream>>>(out, partial);
    kl_final<<<1, 256, 0, stream>>>(partial, out);
}

// Round 24
// 89.714 us; speedup vs baseline: 1.2104x; 1.0571x over previous
//
#include <hip/hip_runtime.h>
#include <stdint.h>

typedef unsigned char u8;
typedef unsigned short u16;
typedef __attribute__((ext_vector_type(8))) short short8;
typedef __attribute__((ext_vector_type(4))) float f32x4;
typedef __attribute__((ext_vector_type(2))) uint32_t u32x2;

#define B_      16
#define L_      1024
#define H_      1024
#define G_      128
#define M_TOT   16368            // B*(L-1)
#define K_TOT   3072
#define OUT_SEG 2095104          // M_TOT*G_
#define KL_IDX  (4*OUT_SEG)
#define KL_BLOCKS 2046           // M_TOT / 8 exactly
#define WSCALE  128.0f
#define WINV    0.0078125f       // 1/128

// ws layout
#define WS_WT_OFF    0           // fp8 W'T [512][3072] = 1,572,864 B
#define WS_BIAS_OFF  1572864     // float[512]
#define WS_PART_OFF  1574912     // float[2046] block partials

__device__ inline void gload16(const void* g, void* l) {
    __builtin_amdgcn_global_load_lds(
        (const __attribute__((address_space(1))) void*)g,
        (__attribute__((address_space(3))) void*)l, 16, 0, 0);
}

// pack 4 floats -> 4 fp8 (e4m3, OCP on gfx950) in one u32, k-ascending bytes
__device__ inline uint32_t pk4fp8(float f0, float f1, float f2, float f3) {
    uint32_t w = __builtin_amdgcn_cvt_pk_fp8_f32(f0, f1, 0, 0);
    w = __builtin_amdgcn_cvt_pk_fp8_f32(f2, f3, w, 1);
    return w;
}

// ---------------- prep: build W'T fp8 (x128) [512][3072] + bias[512] ---------
__global__ __launch_bounds__(256) void prep_kernel(
    const float* __restrict__ Wzm, const float* __restrict__ bzm,
    const float* __restrict__ Wzv, const float* __restrict__ bzv,
    const float* __restrict__ Wqm, const float* __restrict__ bqm,
    const float* __restrict__ Wqv, const float* __restrict__ bqv,
    u8* __restrict__ wt, float* __restrict__ bias)
{
    const int ng = blockIdx.x >> 2;
    const int kq = blockIdx.x & 3;
    const int n0 = ng * 8;
    const float* W; const float* bsrc; int g0; int kmax;
    if (n0 < 128)      { W = Wzm; bsrc = bzm; g0 = n0;       kmax = 2048; }
    else if (n0 < 256) { W = Wzv; bsrc = bzv; g0 = n0 - 128; kmax = 2048; }
    else if (n0 < 384) { W = Wqm; bsrc = bqm; g0 = n0 - 256; kmax = 3072; }
    else               { W = Wqv; bsrc = bqv; g0 = n0 - 384; kmax = 3072; }
    const int tid = threadIdx.x;
    if (kq == 0 && tid < 8) bias[n0 + tid] = bsrc[g0 + tid];

    __shared__ float lt[8][260];
    const int go = tid & 7;
    const int kk = tid >> 3;
    const int nn = tid >> 5;
    const int kc = (tid & 31) * 8;

    for (int i = 0; i < 3; ++i) {
        int kbase = kq * 768 + i * 256;
        __syncthreads();
        #pragma unroll
        for (int kk2 = 0; kk2 < 8; ++kk2) {
            int k = kbase + kk2 * 32 + kk;
            float v = (k < kmax) ? W[(size_t)k * G_ + g0 + go] : 0.0f;
            lt[go][kk2 * 32 + kk] = v;
        }
        __syncthreads();
        uint32_t u0 = pk4fp8(lt[nn][kc + 0] * WSCALE, lt[nn][kc + 1] * WSCALE,
                             lt[nn][kc + 2] * WSCALE, lt[nn][kc + 3] * WSCALE);
        uint32_t u1 = pk4fp8(lt[nn][kc + 4] * WSCALE, lt[nn][kc + 5] * WSCALE,
                             lt[nn][kc + 6] * WSCALE, lt[nn][kc + 7] * WSCALE);
        *(u32x2*)&wt[(size_t)(n0 + nn) * K_TOT + kbase + kc] = (u32x2){u0, u1};
    }
}

// ---------------- GEMM: out[m, 0:512] = ce @ W' + bias (fp8 MFMA) -----------
// R21 champion schedule, fp8 data: BM=128, BN=128, BK=64, 512 threads
// (8 waves, 2x4 of 64x32), grid 512 -> 2 blocks/CU.
//   A: global f32x4 (64B-coalesced) -> P/Q named regs (2-deep) ->
//      cvt_pk_fp8 -> swizzled ds_write_b32 x4.
//   B: fp8 wt via global_load_lds, 16B-granule source-preswizzled.
// Tiles 128 rows x 64 fp8 = 8KB each; LDS = 2*(8+8) = 32KB.
// Swizzle (16B granule): slot16 ^= (row>>1)&3; element k at byte
//   row*64 + (((k>>4)^((row>>1)&3))<<4) + (k&15).
// Counted vmcnt: 5 VMEM/phase (4 A + 1 B); WAITV(5) drains {B(t), A(t+1)}.
__global__ __launch_bounds__(512, 2) void gemm_kernel(
    const float* __restrict__ events, const float* __restrict__ contexts,
    const u8* __restrict__ wt, const float* __restrict__ bias,
    float* __restrict__ out)
{
    __shared__ u8 Ab[2][128 * 64];    // fp8 A tiles, swizzled (8 KB each)
    __shared__ u8 Bs[2][128 * 64];    // fp8 B tiles, swizzled (8 KB each)

    const int tid = threadIdx.x;
    const int bid = blockIdx.x;
    // 4 nb-blocks of an A panel share bid&7 -> same XCD.
    const int xx  = bid & 7;
    const int jj  = bid >> 3;            // 0..63
    const int nb  = jj & 3;
    const int mp  = (jj >> 2) * 8 + xx;  // 0..127
    const int m0  = mp * 128;

    const int lane = tid & 63;
    const int w    = tid >> 6;           // 0..7
    const int wm   = (w >> 2) * 64;      // 0 or 64
    const int wn   = (w & 3) * 32;       // 0,32,64,96
    const int lr   = lane & 15;
    const int kg   = lane >> 4;          // k-octet 0..3

    // ---- A staging: row r = tid>>2 (0..127), quarter q = tid&3 ----
    // Thread holds k = j*16 + q*4 .. +3 for j=0..3 (per-instr 64B/row coalesced)
    const int r = tid >> 2;
    const int q = tid & 3;
    int m = m0 + r; if (m > M_TOT - 1) m = M_TOT - 1;
    int bb = m / 1023;
    int tt = m - bb * 1023;
    const float* paE = events   + ((size_t)(bb * L_ + tt)) * H_;
    const float* paC = contexts + ((size_t)(bb * (L_ - 1) + tt)) * H_;
    // swizzled ds_write_b32 byte offsets
    int aw[4];
    #pragma unroll
    for (int j = 0; j < 4; ++j)
        aw[j] = r * 64 + (((j ^ ((r >> 1) & 3))) << 4) + q * 4;

    // ---- B staging: 1 gload16/thread, source-preswizzled (16B granule) ----
    const int bv   = tid >> 2;           // row 0..127
    const int bc   = tid & 3;            // dest slot16
    const int bcs  = bc ^ ((bv >> 1) & 3);
    const u8* bS = wt + (size_t)(nb * 128 + bv) * K_TOT + bcs * 16;

    // ---- fragment read offsets (bytes; element k = ks*32 + kg*8) ----
    int aoff[4][2], boff[2][2];
    #pragma unroll
    for (int i = 0; i < 4; ++i) {
        int row = wm + i * 16 + lr;
        #pragma unroll
        for (int ks = 0; ks < 2; ++ks) {
            int c16 = ks * 2 + (kg >> 1);
            aoff[i][ks] = row * 64 + ((c16 ^ ((row >> 1) & 3)) << 4) + (kg & 1) * 8;
        }
    }
    #pragma unroll
    for (int j = 0; j < 2; ++j) {
        int nn = wn + j * 16 + lr;
        #pragma unroll
        for (int ks = 0; ks < 2; ++ks) {
            int c16 = ks * 2 + (kg >> 1);
            boff[j][ks] = nn * 64 + ((c16 ^ ((nn >> 1) & 3)) << 4) + (kg & 1) * 8;
        }
    }

    f32x4 acc[4][2];
    #pragma unroll
    for (int i = 0; i < 4; ++i)
        #pragma unroll
        for (int j = 0; j < 2; ++j)
            acc[i][j] = (f32x4){0.f, 0.f, 0.f, 0.f};

    auto stageB = [&](int buf, int kt) {
        gload16(bS + kt * 64, &Bs[buf][tid * 16]);
    };
    auto compute = [&](int buf) {
        #pragma unroll
        for (int ks = 0; ks < 2; ++ks) {
            long a[4], bf[2];
            #pragma unroll
            for (int i = 0; i < 4; ++i)
                a[i] = *(const long*)&Ab[buf][aoff[i][ks]];
            #pragma unroll
            for (int j = 0; j < 2; ++j)
                bf[j] = *(const long*)&Bs[buf][boff[j][ks]];
            __builtin_amdgcn_s_setprio(1);
            #pragma unroll
            for (int i = 0; i < 4; ++i)
                #pragma unroll
                for (int j = 0; j < 2; ++j)
                    acc[i][j] = __builtin_amdgcn_mfma_f32_16x16x32_fp8_fp8(
                        a[i], bf[j], acc[i][j], 0, 0, 0);
            __builtin_amdgcn_s_setprio(0);
        }
    };

    // Named A-staging register sets (2-phase-deep; no arrays -> no scratch)
    f32x4 P0, P1, P2, P3;
    f32x4 Q0, Q1, Q2, Q3;

#define LOADA(p, KT)                                                           \
    {                                                                          \
        int k0_ = (KT) * 64;                                                   \
        int rg_ = (KT) >> 4;                                                   \
        int kq_ = (k0_ & 1023) + q * 4;                                        \
        const float* s_ = (rg_ == 0) ? paE : (rg_ == 1 ? (paE + H_) : paC);    \
        s_ += kq_;                                                             \
        p##0 = *(const f32x4*)(s_ +  0);                                       \
        p##1 = *(const f32x4*)(s_ + 16);                                       \
        p##2 = *(const f32x4*)(s_ + 32);                                       \
        p##3 = *(const f32x4*)(s_ + 48);                                       \
    }
#define CVT1(p, J, BUF)                                                        \
    {                                                                          \
        uint32_t w_ = pk4fp8(p##J[0], p##J[1], p##J[2], p##J[3]);              \
        *(uint32_t*)&Ab[BUF][aw[J]] = w_;                                      \
    }
#define CVTW(p, BUF)  CVT1(p, 0, BUF) CVT1(p, 1, BUF) CVT1(p, 2, BUF) CVT1(p, 3, BUF)

#define WAITV(N)                                                               \
    asm volatile("s_waitcnt vmcnt(" #N ")" ::: "memory");                      \
    __builtin_amdgcn_sched_barrier(0);
#define LGKM0                                                                  \
    asm volatile("s_waitcnt lgkmcnt(0)" ::: "memory");                         \
    __builtin_amdgcn_sched_barrier(0);
#define BAR __builtin_amdgcn_s_barrier()

    // prologue: A(0)->regs->Ab[0]; B(0) in flight; A(1)->Q (in flight)
    LOADA(P, 0);
    stageB(0, 0);
    WAITV(1);            // drain P = A(0) regs, leave B(0)
    CVTW(P, 0);
    LOADA(Q, 1);         // outstanding: B(0) 1 + Q 4 = 5
    LGKM0;               // prologue ds_writes done before first barrier

    for (int t = 0; t < 46; t += 2) {
        // phase t (buf0): consume Q=A(t+1) after WAITV
        LOADA(P, t + 2);
        stageB(1, t + 1);
        WAITV(5); BAR;                 // drains B(t) + Q regs
        compute(0);
        CVTW(Q, 1);
        LGKM0; BAR;
        // phase t+1 (buf1)
        LOADA(Q, t + 3);
        stageB(0, t + 2);
        WAITV(5); BAR;                 // drains B(t+1) + P regs
        compute(1);
        CVTW(P, 0);
        LGKM0; BAR;
    }
    // phase 46 (buf0): Q holds A(47); no more A loads
    stageB(1, 47);
    WAITV(1); BAR;                     // drains B(46) + Q regs, leaves B(47)
    compute(0);
    CVTW(Q, 1);
    LGKM0; BAR;
    // phase 47 (buf1)
    WAITV(0); BAR;
    compute(1);

#undef LOADA
#undef CVT1
#undef CVTW
#undef WAITV
#undef LGKM0
#undef BAR

    // epilogue: row = m0 + wm + i*16 + kg*4 + rr ; gcol = nb*128 + wn + j*16 + lr
    // un-scale W (x128) by WINV.
    const float* bptr = bias + nb * 128;
    float* obase = out + (size_t)nb * OUT_SEG;
    #pragma unroll
    for (int i = 0; i < 4; ++i) {
        int mloc = wm + i * 16 + kg * 4;
        #pragma unroll
        for (int j = 0; j < 2; ++j) {
            int g = wn + j * 16 + lr;
            float bv2 = bptr[g];
            #pragma unroll
            for (int rr = 0; rr < 4; ++rr) {
                int mo = m0 + mloc + rr;
                if (mo < M_TOT)
                    obase[(size_t)mo * G_ + g] = acc[i][j][rr] * WINV + bv2;
            }
        }
    }
}

// ---------------- KL reduction: stage 1 (f32x4 loads, 8 rows/block) ----------
__global__ __launch_bounds__(256) void kl_kernel(const float* __restrict__ out,
                                                 float* __restrict__ partial)
{
    int row  = blockIdx.x * 8 + (threadIdx.x >> 5);   // 2046*8 = M_TOT
    int col  = (threadIdx.x & 31) * 4;
    const float* zm  = out;
    const float* zlv = out + OUT_SEG;
    const float* qm  = out + (size_t)2 * OUT_SEG;
    const float* qlv = out + (size_t)3 * OUT_SEG;
    size_t base = (size_t)row * G_ + col;
    f32x4 a = *(const f32x4*)&zm[base];
    f32x4 b = *(const f32x4*)&zlv[base];
    f32x4 c = *(const f32x4*)&qm[base];
    f32x4 d = *(const f32x4*)&qlv[base];
    float s = 0.f;
    #pragma unroll
    for (int e = 0; e < 4; ++e) {
        float diff = a[e] - c[e];
        s += d[e] - b[e] + (__expf(b[e]) + diff * diff) * __expf(-d[e]) - 1.0f;
    }
    #pragma unroll
    for (int off = 32; off > 0; off >>= 1)
        s += __shfl_down(s, off);
    __shared__ float pw[4];
    int wid  = threadIdx.x >> 6;
    int lane = threadIdx.x & 63;
    if (lane == 0) pw[wid] = s;
    __syncthreads();
    if (threadIdx.x == 0)
        partial[blockIdx.x] = pw[0] + pw[1] + pw[2] + pw[3];
}

// ---------------- KL reduction: stage 2 --------------------------------------
__global__ __launch_bounds__(256) void kl_final(const float* __restrict__ partial,
                                                float* __restrict__ out)
{
    float s = 0.f;
    for (int i = threadIdx.x; i < KL_BLOCKS; i += 256) s += partial[i];
    #pragma unroll
    for (int off = 32; off > 0; off >>= 1)
        s += __shfl_down(s, off);
    __shared__ float pw[4];
    int wid = threadIdx.x >> 6;
    int lane = threadIdx.x & 63;
    if (lane == 0) pw[wid] = s;
    __syncthreads();
    if (threadIdx.x == 0)
        out[KL_IDX] = 0.5f * (pw[0] + pw[1] + pw[2] + pw[3]) / (float)M_TOT;
}

// ---------------- launcher ----------------------------------------------------
extern "C" void kernel_launch(void* const* d_in, const int* in_sizes, int n_in,
                              void* d_out, int out_size, void* d_ws, size_t ws_size,
                              hipStream_t stream)
{
    const float* events   = (const float*)d_in[0];
    const float* contexts = (const float*)d_in[1];
    const float* Wzm = (const float*)d_in[2];
    const float* bzm = (const float*)d_in[3];
    const float* Wzv = (const float*)d_in[4];
    const float* bzv = (const float*)d_in[5];
    const float* Wqm = (const float*)d_in[6];
    const float* bqm = (const float*)d_in[7];
    const float* Wqv = (const float*)d_in[8];
    const float* bqv = (const float*)d_in[9];
    float* out = (float*)d_out;

    u8*    wt      = (u8*)((char*)d_ws + WS_WT_OFF);
    float* bias    = (float*)((char*)d_ws + WS_BIAS_OFF);
    float* partial = (float*)((char*)d_ws + WS_PART_OFF);

    prep_kernel<<<256, 256, 0, stream>>>(Wzm, bzm, Wzv, bzv, Wqm, bqm, Wqv, bqv,
                                         wt, bias);
    gemm_kernel<<<512, 512, 0, stream>>>(events, contexts, wt, bias, out);
    kl_kernel<<<KL_BLOCKS, 256, 0, stream>>>(out, partial);
    kl_final<<<1, 256, 0, stream>>>(partial, out);
}